// Round 2
// baseline (13264.589 us; speedup 1.0000x reference)
//
#include <hip/hip_runtime.h>
#include <hip/hip_bf16.h>

typedef __attribute__((ext_vector_type(8))) short bf16x8;   // 8 bf16 (4 VGPRs) MFMA A/B frag
typedef __attribute__((ext_vector_type(4))) float floatx4;  // MFMA C/D frag

#define MFMA_BF16_16x16x32(a, b, c) __builtin_amdgcn_mfma_f32_16x16x32_bf16((a), (b), (c), 0, 0, 0)

#define B_SZ 64
#define T_SZ 512
#define DIN  1024
#define DH   2048
#define DOUT 1024
#define NBLK 128   // persistent grid: 128 blocks x 256 thr -> 1 block/CU, co-resident

__device__ inline bf16x8 cvt8(float4 a, float4 b) {
  union { bf16x8 v; __hip_bfloat16 h[8]; } u;
  u.h[0] = __float2bfloat16(a.x); u.h[1] = __float2bfloat16(a.y);
  u.h[2] = __float2bfloat16(a.z); u.h[3] = __float2bfloat16(a.w);
  u.h[4] = __float2bfloat16(b.x); u.h[5] = __float2bfloat16(b.y);
  u.h[6] = __float2bfloat16(b.z); u.h[7] = __float2bfloat16(b.w);
  return u.v;
}

// ---------------------------------------------------------------------------
// fp32 -> bf16 quantize (RNE), 8 elems/thread. n must be a multiple of 8.
// ---------------------------------------------------------------------------
__global__ __launch_bounds__(256) void f32_to_bf16(
    const float* __restrict__ in, __hip_bfloat16* __restrict__ out, long n)
{
  long i = ((long)blockIdx.x * 256 + threadIdx.x) * 8;
  if (i + 8 <= n) {
    float4 a = *(const float4*)(in + i);
    float4 b = *(const float4*)(in + i + 4);
    *(bf16x8*)(out + i) = cvt8(a, b);
  }
}

// ---------------------------------------------------------------------------
// Kernel 1: XH[m][n] = sum_k X[m][k] * Wxh[n][k] + bxh[n]   (X, Wxh fp32!)
//   M=32768 (b*512+t), N=2048, K=1024. 128x128 tile, BK=64, 4 waves 2x2,
//   fp32 global loads converted to bf16 during LDS staging. XH out bf16.
// ---------------------------------------------------------------------------
__global__ __launch_bounds__(256) void xh_gemm(
    const float* __restrict__ X,
    const float* __restrict__ W,
    const float* __restrict__ bias,
    __hip_bfloat16* __restrict__ XH)
{
  const int K = DIN;   // 1024
  const int N = DH;    // 2048
  __shared__ __hip_bfloat16 As[128][64];
  __shared__ __hip_bfloat16 Bs[128][64];

  const int nb  = N / 128;              // 16
  const int bm  = blockIdx.x / nb;
  const int bn  = blockIdx.x % nb;
  const int m0  = bm * 128, n0 = bn * 128;
  const int tid = threadIdx.x;
  const int lane = tid & 63;
  const int wave = tid >> 6;
  const int wm  = (wave >> 1) * 64;
  const int wn  = (wave & 1) * 64;
  const int col = lane & 15;
  const int quad = lane >> 4;

  const floatx4 Z = {0.f, 0.f, 0.f, 0.f};
  floatx4 acc[4][4];
  #pragma unroll
  for (int i = 0; i < 4; ++i)
    #pragma unroll
    for (int j = 0; j < 4; ++j) acc[i][j] = Z;

  const int srow = tid >> 3;            // 0..31
  const int scol = (tid & 7) * 8;       // 0..56 step 8

  for (int k0 = 0; k0 < K; k0 += 64) {
    __syncthreads();
    #pragma unroll
    for (int p = 0; p < 4; ++p) {
      int r = srow + p * 32;
      const float* xs = &X[(long)(m0 + r) * K + k0 + scol];
      const float* wsrc = &W[(long)(n0 + r) * K + k0 + scol];
      *(bf16x8*)(&As[r][scol]) = cvt8(*(const float4*)xs,   *(const float4*)(xs + 4));
      *(bf16x8*)(&Bs[r][scol]) = cvt8(*(const float4*)wsrc, *(const float4*)(wsrc + 4));
    }
    __syncthreads();
    #pragma unroll
    for (int kk = 0; kk < 64; kk += 32) {
      const int kr = kk + quad * 8;
      bf16x8 a[4], b[4];
      #pragma unroll
      for (int i = 0; i < 4; ++i) a[i] = *(const bf16x8*)(&As[wm + i*16 + col][kr]);
      #pragma unroll
      for (int j = 0; j < 4; ++j) b[j] = *(const bf16x8*)(&Bs[wn + j*16 + col][kr]);
      #pragma unroll
      for (int i = 0; i < 4; ++i)
        #pragma unroll
        for (int j = 0; j < 4; ++j)
          acc[i][j] = MFMA_BF16_16x16x32(a[i], b[j], acc[i][j]);
    }
  }

  // Epilogue: C/D layout col=lane&15 (n), row=quad*4+r (m). fp32 bias, bf16 out.
  #pragma unroll
  for (int j = 0; j < 4; ++j) {
    const int n = n0 + wn + j*16 + col;
    const float bv = bias[n];
    #pragma unroll
    for (int i = 0; i < 4; ++i) {
      const int mr = m0 + wm + i*16 + quad*4;
      #pragma unroll
      for (int r = 0; r < 4; ++r)
        XH[(long)(mr + r) * N + n] = __float2bfloat16(acc[i][j][r] + bv);
    }
  }
}

// ---------------------------------------------------------------------------
// Grid barrier: monotonic counter. Relaxed spin (acquire-per-poll would emit
// buffer_inv each poll and thrash the XCD's L2); acquire fence after exit.
// ---------------------------------------------------------------------------
__device__ inline void grid_barrier(unsigned* bar, unsigned* target) {
  __syncthreads();
  *target += NBLK;
  if (threadIdx.x == 0) {
    __threadfence();  // publish this block's h stores (wbl2)
    __hip_atomic_fetch_add(bar, 1u, __ATOMIC_RELEASE, __HIP_MEMORY_SCOPE_AGENT);
    while (__hip_atomic_load(bar, __ATOMIC_RELAXED, __HIP_MEMORY_SCOPE_AGENT) < *target)
      __builtin_amdgcn_s_sleep(2);
    __threadfence();  // invalidate stale cached h (inv)
  }
  __syncthreads();
}

// ---------------------------------------------------------------------------
// Kernel 2: persistent Elman recurrence + final projection.
//   Block bid owns h columns [bid*16, bid*16+16). 1 block/CU -> 1 wave/SIMD
//   -> ~512 VGPR/wave budget: each lane's 16 Whh B-frags (64 VGPR) are
//   preloaded into registers once; zero per-step W traffic. 4 waves split
//   K=2048; LDS cross-wave reduce; + xh_t, relu, bf16 ping-pong h.
//   Final y = h @ Why^T + bhy written fp32 to d_out.
// ---------------------------------------------------------------------------
__global__ __launch_bounds__(256) void elman_persistent(
    const __hip_bfloat16* __restrict__ XH,    // [64][512][2048] bf16
    const __hip_bfloat16* __restrict__ Whh,   // [2048][2048] bf16
    const __hip_bfloat16* __restrict__ Why,   // [1024][2048] bf16
    const float* __restrict__ bhy,            // [1024] fp32
    __hip_bfloat16* __restrict__ hbuf,        // [2][64][2048] bf16
    float* __restrict__ Y,                    // [64][1024] fp32 = d_out
    unsigned* __restrict__ bar)
{
  __shared__ float partial[4][64][16];
  const int tid  = threadIdx.x;
  const int lane = tid & 63;
  const int wave = tid >> 6;
  const int n0   = blockIdx.x * 16;
  const int col  = lane & 15;
  const int quad = lane >> 4;
  const int kw   = wave * 512;      // this wave's K range base
  unsigned target = 0;

  const int mrow = tid >> 2;        // reduction: batch row b (0..63)
  const int mcol = (tid & 3) * 4;   // reduction: col base within 16-slice

  // Preload this lane's 16 Whh B-frags into registers (stream-ordered after conv).
  bf16x8 wreg[16];
  {
    const __hip_bfloat16* wrow = Whh + (long)(n0 + col) * DH + kw + quad * 8;
    #pragma unroll
    for (int kk16 = 0; kk16 < 16; ++kk16)
      wreg[kk16] = *(const bf16x8*)(wrow + kk16 * 32);
  }

  // h0 = 0 for our column slice (buffer 0)
  #pragma unroll
  for (int r = 0; r < 4; ++r)
    hbuf[(long)mrow * DH + n0 + mcol + r] = __float2bfloat16(0.f);
  grid_barrier(bar, &target);

  int cur = 0;
  const floatx4 Z = {0.f, 0.f, 0.f, 0.f};

  for (int t = 0; t < T_SZ; ++t) {
    const __hip_bfloat16* h = hbuf + (long)cur * (B_SZ * DH);
    const __hip_bfloat16* hrow = h + (long)col * DH + kw + quad * 8;
    floatx4 acc[4];
    acc[0] = Z; acc[1] = Z; acc[2] = Z; acc[3] = Z;
    #pragma unroll
    for (int kk16 = 0; kk16 < 16; ++kk16) {
      const bf16x8 b = wreg[kk16];
      #pragma unroll
      for (int i = 0; i < 4; ++i) {
        bf16x8 a = *(const bf16x8*)(hrow + (long)i * 16 * DH + kk16 * 32);
        acc[i] = MFMA_BF16_16x16x32(a, b, acc[i]);
      }
    }
    // partials to LDS (C/D layout: m = i*16 + quad*4 + r, n = col)
    #pragma unroll
    for (int i = 0; i < 4; ++i)
      #pragma unroll
      for (int r = 0; r < 4; ++r)
        partial[wave][i*16 + quad*4 + r][col] = acc[i][r];
    __syncthreads();
    // reduce 4 waves, add xh_t, relu, store bf16 h_next
    {
      __hip_bfloat16* hn = hbuf + (long)(1 - cur) * (B_SZ * DH);
      const __hip_bfloat16* xrow = XH + ((long)mrow * T_SZ + t) * DH + n0 + mcol;
      #pragma unroll
      for (int r = 0; r < 4; ++r) {
        float v = partial[0][mrow][mcol + r] + partial[1][mrow][mcol + r]
                + partial[2][mrow][mcol + r] + partial[3][mrow][mcol + r];
        v += __bfloat162float(xrow[r]);
        v = v > 0.f ? v : 0.f;
        hn[(long)mrow * DH + n0 + mcol + r] = __float2bfloat16(v);
      }
    }
    grid_barrier(bar, &target);
    cur = 1 - cur;
  }

  // Final projection: y = h_final @ Why^T + bhy  (blocks 0..63, fp32 out)
  if (n0 < DOUT) {
    const __hip_bfloat16* h = hbuf + (long)cur * (B_SZ * DH);
    const __hip_bfloat16* hrow = h   + (long)col * DH        + kw + quad * 8;
    const __hip_bfloat16* wrow = Why + (long)(n0 + col) * DH + kw + quad * 8;
    floatx4 acc[4];
    acc[0] = Z; acc[1] = Z; acc[2] = Z; acc[3] = Z;
    #pragma unroll
    for (int kk16 = 0; kk16 < 16; ++kk16) {
      bf16x8 b = *(const bf16x8*)(wrow + kk16 * 32);
      #pragma unroll
      for (int i = 0; i < 4; ++i) {
        bf16x8 a = *(const bf16x8*)(hrow + (long)i * 16 * DH + kk16 * 32);
        acc[i] = MFMA_BF16_16x16x32(a, b, acc[i]);
      }
    }
    #pragma unroll
    for (int i = 0; i < 4; ++i)
      #pragma unroll
      for (int r = 0; r < 4; ++r)
        partial[wave][i*16 + quad*4 + r][col] = acc[i][r];
    __syncthreads();
    #pragma unroll
    for (int r = 0; r < 4; ++r) {
      float v = partial[0][mrow][mcol + r] + partial[1][mrow][mcol + r]
              + partial[2][mrow][mcol + r] + partial[3][mrow][mcol + r];
      Y[(long)mrow * DOUT + n0 + mcol + r] = v + bhy[n0 + mcol + r];
    }
  }
}

// ---------------------------------------------------------------------------
extern "C" void kernel_launch(void* const* d_in, const int* in_sizes, int n_in,
                              void* d_out, int out_size, void* d_ws, size_t ws_size,
                              hipStream_t stream) {
  const float* x   = (const float*)d_in[0];   // [64][512][1024] fp32
  const float* Wxh = (const float*)d_in[1];   // [2048][1024]    fp32
  const float* bxh = (const float*)d_in[2];   // [2048]          fp32
  const float* Whh = (const float*)d_in[3];   // [2048][2048]    fp32
  const float* Why = (const float*)d_in[4];   // [1024][2048]    fp32
  const float* bhy = (const float*)d_in[5];   // [1024]          fp32
  float* y = (float*)d_out;                   // [64][1024]      fp32

  char* ws = (char*)d_ws;
  const size_t XH_BYTES  = (size_t)B_SZ * T_SZ * DH * 2;   // 128 MiB
  const size_t WHH_BYTES = (size_t)DH * DH * 2;            // 8 MiB
  const size_t WHY_BYTES = (size_t)DOUT * DH * 2;          // 4 MiB
  const size_t H_BYTES   = (size_t)2 * B_SZ * DH * 2;      // 512 KiB
  __hip_bfloat16* XH     = (__hip_bfloat16*)ws;
  __hip_bfloat16* Whh_bf = (__hip_bfloat16*)(ws + XH_BYTES);
  __hip_bfloat16* Why_bf = (__hip_bfloat16*)(ws + XH_BYTES + WHH_BYTES);
  __hip_bfloat16* hbuf   = (__hip_bfloat16*)(ws + XH_BYTES + WHH_BYTES + WHY_BYTES);
  unsigned* bar          = (unsigned*)(ws + XH_BYTES + WHH_BYTES + WHY_BYTES + H_BYTES);

  hipMemsetAsync(bar, 0, sizeof(unsigned), stream);
  f32_to_bf16<<<dim3((DH*DH)/(256*8)),   dim3(256), 0, stream>>>(Whh, Whh_bf, (long)DH*DH);
  f32_to_bf16<<<dim3((DOUT*DH)/(256*8)), dim3(256), 0, stream>>>(Why, Why_bf, (long)DOUT*DH);
  xh_gemm<<<dim3((32768/128) * (DH/128)), dim3(256), 0, stream>>>(x, Wxh, bxh, XH);
  elman_persistent<<<dim3(NBLK), dim3(256), 0, stream>>>(XH, Whh_bf, Why_bf, bhy, hbuf, y, bar);
}

// Round 3
// 10072.279 us; speedup vs baseline: 1.3169x; 1.3169x over previous
//
#include <hip/hip_runtime.h>
#include <hip/hip_bf16.h>

typedef __attribute__((ext_vector_type(8))) short bf16x8;   // 8 bf16 (4 VGPRs) MFMA A/B frag
typedef __attribute__((ext_vector_type(4))) float floatx4;  // MFMA C/D frag

#define MFMA_BF16_16x16x32(a, b, c) __builtin_amdgcn_mfma_f32_16x16x32_bf16((a), (b), (c), 0, 0, 0)

#define B_SZ 64
#define T_SZ 512
#define DIN  1024
#define DH   2048
#define DOUT 1024
#define NBLK 64    // persistent grid: 64 blocks x 256 thr -> 1 block/CU, co-resident
#define COLS 32    // h columns owned per block (64*32 = 2048)

__device__ inline bf16x8 cvt8(float4 a, float4 b) {
  union { bf16x8 v; __hip_bfloat16 h[8]; } u;
  u.h[0] = __float2bfloat16(a.x); u.h[1] = __float2bfloat16(a.y);
  u.h[2] = __float2bfloat16(a.z); u.h[3] = __float2bfloat16(a.w);
  u.h[4] = __float2bfloat16(b.x); u.h[5] = __float2bfloat16(b.y);
  u.h[6] = __float2bfloat16(b.z); u.h[7] = __float2bfloat16(b.w);
  return u.v;
}

// Coherent (MALL-routed) h access: relaxed agent-scope atomics compile to
// global_load/store_dwordx2 with sc0+sc1 -> bypass L1/L2, land in the
// memory-side Infinity Cache = the cross-XCD coherence point. No fences.
__device__ inline bf16x8 load_h16(const __hip_bfloat16* p) {
  union { bf16x8 v; unsigned long long q[2]; } u;
  const unsigned long long* q = (const unsigned long long*)p;
  u.q[0] = __hip_atomic_load(q,     __ATOMIC_RELAXED, __HIP_MEMORY_SCOPE_AGENT);
  u.q[1] = __hip_atomic_load(q + 1, __ATOMIC_RELAXED, __HIP_MEMORY_SCOPE_AGENT);
  return u.v;
}

// ---------------------------------------------------------------------------
// fp32 -> bf16 quantize (RNE), 8 elems/thread.
// ---------------------------------------------------------------------------
__global__ __launch_bounds__(256) void f32_to_bf16(
    const float* __restrict__ in, __hip_bfloat16* __restrict__ out, long n)
{
  long i = ((long)blockIdx.x * 256 + threadIdx.x) * 8;
  if (i + 8 <= n) {
    float4 a = *(const float4*)(in + i);
    float4 b = *(const float4*)(in + i + 4);
    *(bf16x8*)(out + i) = cvt8(a, b);
  }
}

// ---------------------------------------------------------------------------
// Kernel 1: XH = X @ Wxh^T + bxh  (fp32 in, bf16 out). 128x128 tile, BK=64.
// ---------------------------------------------------------------------------
__global__ __launch_bounds__(256) void xh_gemm(
    const float* __restrict__ X,
    const float* __restrict__ W,
    const float* __restrict__ bias,
    __hip_bfloat16* __restrict__ XH)
{
  const int K = DIN;
  const int N = DH;
  __shared__ __hip_bfloat16 As[128][64];
  __shared__ __hip_bfloat16 Bs[128][64];

  const int nb  = N / 128;
  const int bm  = blockIdx.x / nb;
  const int bn  = blockIdx.x % nb;
  const int m0  = bm * 128, n0 = bn * 128;
  const int tid = threadIdx.x;
  const int lane = tid & 63;
  const int wave = tid >> 6;
  const int wm  = (wave >> 1) * 64;
  const int wn  = (wave & 1) * 64;
  const int col = lane & 15;
  const int quad = lane >> 4;

  const floatx4 Z = {0.f, 0.f, 0.f, 0.f};
  floatx4 acc[4][4];
  #pragma unroll
  for (int i = 0; i < 4; ++i)
    #pragma unroll
    for (int j = 0; j < 4; ++j) acc[i][j] = Z;

  const int srow = tid >> 3;
  const int scol = (tid & 7) * 8;

  for (int k0 = 0; k0 < K; k0 += 64) {
    __syncthreads();
    #pragma unroll
    for (int p = 0; p < 4; ++p) {
      int r = srow + p * 32;
      const float* xs = &X[(long)(m0 + r) * K + k0 + scol];
      const float* wsrc = &W[(long)(n0 + r) * K + k0 + scol];
      *(bf16x8*)(&As[r][scol]) = cvt8(*(const float4*)xs,   *(const float4*)(xs + 4));
      *(bf16x8*)(&Bs[r][scol]) = cvt8(*(const float4*)wsrc, *(const float4*)(wsrc + 4));
    }
    __syncthreads();
    #pragma unroll
    for (int kk = 0; kk < 64; kk += 32) {
      const int kr = kk + quad * 8;
      bf16x8 a[4], b[4];
      #pragma unroll
      for (int i = 0; i < 4; ++i) a[i] = *(const bf16x8*)(&As[wm + i*16 + col][kr]);
      #pragma unroll
      for (int j = 0; j < 4; ++j) b[j] = *(const bf16x8*)(&Bs[wn + j*16 + col][kr]);
      #pragma unroll
      for (int i = 0; i < 4; ++i)
        #pragma unroll
        for (int j = 0; j < 4; ++j)
          acc[i][j] = MFMA_BF16_16x16x32(a[i], b[j], acc[i][j]);
    }
  }

  #pragma unroll
  for (int j = 0; j < 4; ++j) {
    const int n = n0 + wn + j*16 + col;
    const float bv = bias[n];
    #pragma unroll
    for (int i = 0; i < 4; ++i) {
      const int mr = m0 + wm + i*16 + quad*4;
      #pragma unroll
      for (int r = 0; r < 4; ++r)
        XH[(long)(mr + r) * N + n] = __float2bfloat16(acc[i][j][r] + bv);
    }
  }
}

// ---------------------------------------------------------------------------
// Fence-free grid barrier. h stores already bypass L2 (sc0 sc1), so release
// = drain own stores to the coherence point (vmcnt 0); acquire = nothing,
// because h loads also bypass L1/L2. NO buffer_wbl2 / buffer_inv per step.
// ---------------------------------------------------------------------------
__device__ inline void grid_barrier(unsigned* bar, unsigned* target) {
  asm volatile("s_waitcnt vmcnt(0)" ::: "memory");  // own sc-stores at MALL
  __syncthreads();
  *target += NBLK;
  if (threadIdx.x == 0) {
    __hip_atomic_fetch_add(bar, 1u, __ATOMIC_RELAXED, __HIP_MEMORY_SCOPE_AGENT);
    while (__hip_atomic_load(bar, __ATOMIC_RELAXED, __HIP_MEMORY_SCOPE_AGENT) < *target)
      __builtin_amdgcn_s_sleep(1);
  }
  __syncthreads();
}

// ---------------------------------------------------------------------------
// Kernel 2: persistent Elman recurrence + final projection.
//   64 blocks; block bid owns h cols [bid*32, bid*32+32). 1 block/CU,
//   __launch_bounds__(256,1) -> full VGPR budget: Whh slice (2 n-tiles x
//   16 k-chunks = 128 VGPRs) pinned in registers. 4 waves split K=2048.
//   h exchanged via MALL (sc-flagged), zero per-step cache maintenance.
// ---------------------------------------------------------------------------
__global__ __launch_bounds__(256, 1) void elman_persistent(
    const __hip_bfloat16* __restrict__ XH,    // [64][512][2048] bf16
    const __hip_bfloat16* __restrict__ Whh,   // [2048][2048] bf16
    const __hip_bfloat16* __restrict__ Why,   // [1024][2048] bf16
    const float* __restrict__ bhy,            // [1024] fp32
    __hip_bfloat16* __restrict__ hbuf,        // [2][64][2048] bf16
    float* __restrict__ Y,                    // [64][1024] fp32 = d_out
    unsigned* __restrict__ bar)
{
  __shared__ float partial[4][64][33];        // +1 pad: kill 4-way write conflict
  const int tid  = threadIdx.x;
  const int lane = tid & 63;
  const int wave = tid >> 6;
  const int n0   = blockIdx.x * COLS;
  const int col  = lane & 15;
  const int quad = lane >> 4;
  const int kw   = wave * 512;
  unsigned target = 0;

  const int mrow = tid >> 2;        // reduce/store: batch row (0..63)
  const int mcol = (tid & 3) * 8;   // reduce/store: col base within 32-slice

  // Pin Whh B-frags in registers: 2 n-tiles x 16 k-chunks = 128 VGPRs.
  bf16x8 wreg[2][16];
  #pragma unroll
  for (int n = 0; n < 2; ++n) {
    const __hip_bfloat16* wrow = Whh + (long)(n0 + n*16 + col) * DH + kw + quad * 8;
    #pragma unroll
    for (int k16 = 0; k16 < 16; ++k16)
      wreg[n][k16] = *(const bf16x8*)(wrow + k16 * 32);
  }

  // h0 = 0 for our slice (buffer 0), via coherent stores
  {
    unsigned long long* hp = (unsigned long long*)(hbuf + (long)mrow * DH + n0 + mcol);
    __hip_atomic_store(hp,     0ull, __ATOMIC_RELAXED, __HIP_MEMORY_SCOPE_AGENT);
    __hip_atomic_store(hp + 1, 0ull, __ATOMIC_RELAXED, __HIP_MEMORY_SCOPE_AGENT);
  }
  grid_barrier(bar, &target);

  int cur = 0;
  const floatx4 Z = {0.f, 0.f, 0.f, 0.f};

  for (int t = 0; t < T_SZ; ++t) {
    const __hip_bfloat16* h = hbuf + (long)cur * (B_SZ * DH);
    const __hip_bfloat16* hrow = h + (long)col * DH + kw + quad * 8;
    floatx4 acc[4][2];
    #pragma unroll
    for (int i = 0; i < 4; ++i) { acc[i][0] = Z; acc[i][1] = Z; }

    #pragma unroll
    for (int k16 = 0; k16 < 16; ++k16) {
      #pragma unroll
      for (int i = 0; i < 4; ++i) {
        bf16x8 a = load_h16(hrow + (long)i * 16 * DH + k16 * 32);
        acc[i][0] = MFMA_BF16_16x16x32(a, wreg[0][k16], acc[i][0]);
        acc[i][1] = MFMA_BF16_16x16x32(a, wreg[1][k16], acc[i][1]);
      }
    }
    // partials to LDS (C/D: m = i*16+quad*4+r, n = ntile*16+col)
    #pragma unroll
    for (int i = 0; i < 4; ++i)
      #pragma unroll
      for (int n = 0; n < 2; ++n)
        #pragma unroll
        for (int r = 0; r < 4; ++r)
          partial[wave][i*16 + quad*4 + r][n*16 + col] = acc[i][n][r];
    __syncthreads();
    // reduce 4 waves, + xh_t, relu, coherent-store bf16 h_next (8/thread)
    {
      __hip_bfloat16* hn = hbuf + (long)(1 - cur) * (B_SZ * DH);
      const __hip_bfloat16* xrow = XH + ((long)mrow * T_SZ + t) * DH + n0 + mcol;
      union { bf16x8 v8; __hip_bfloat16 hh[8]; unsigned long long q[2]; } o;
      bf16x8 xv = *(const bf16x8*)xrow;
      union { bf16x8 v8; __hip_bfloat16 hh[8]; } xu; xu.v8 = xv;
      #pragma unroll
      for (int c = 0; c < 8; ++c) {
        float v = partial[0][mrow][mcol + c] + partial[1][mrow][mcol + c]
                + partial[2][mrow][mcol + c] + partial[3][mrow][mcol + c];
        v += __bfloat162float(xu.hh[c]);
        v = v > 0.f ? v : 0.f;
        o.hh[c] = __float2bfloat16(v);
      }
      unsigned long long* hp = (unsigned long long*)(hn + (long)mrow * DH + n0 + mcol);
      __hip_atomic_store(hp,     o.q[0], __ATOMIC_RELAXED, __HIP_MEMORY_SCOPE_AGENT);
      __hip_atomic_store(hp + 1, o.q[1], __ATOMIC_RELAXED, __HIP_MEMORY_SCOPE_AGENT);
    }
    grid_barrier(bar, &target);   // drains stores + separates read/write phases
    cur = 1 - cur;
  }

  // Final projection: y = h_final @ Why^T + bhy  (blocks 0..31, fp32 out)
  if (n0 < DOUT) {
    const __hip_bfloat16* h = hbuf + (long)cur * (B_SZ * DH);
    const __hip_bfloat16* hrow = h + (long)col * DH + kw + quad * 8;
    floatx4 acc[4][2];
    #pragma unroll
    for (int i = 0; i < 4; ++i) { acc[i][0] = Z; acc[i][1] = Z; }
    #pragma unroll
    for (int k16 = 0; k16 < 16; ++k16) {
      bf16x8 b0 = *(const bf16x8*)(Why + (long)(n0 +      col) * DH + kw + quad*8 + k16*32);
      bf16x8 b1 = *(const bf16x8*)(Why + (long)(n0 + 16 + col) * DH + kw + quad*8 + k16*32);
      #pragma unroll
      for (int i = 0; i < 4; ++i) {
        bf16x8 a = load_h16(hrow + (long)i * 16 * DH + k16 * 32);
        acc[i][0] = MFMA_BF16_16x16x32(a, b0, acc[i][0]);
        acc[i][1] = MFMA_BF16_16x16x32(a, b1, acc[i][1]);
      }
    }
    #pragma unroll
    for (int i = 0; i < 4; ++i)
      #pragma unroll
      for (int n = 0; n < 2; ++n)
        #pragma unroll
        for (int r = 0; r < 4; ++r)
          partial[wave][i*16 + quad*4 + r][n*16 + col] = acc[i][n][r];
    __syncthreads();
    #pragma unroll
    for (int c = 0; c < 8; ++c) {
      float v = partial[0][mrow][mcol + c] + partial[1][mrow][mcol + c]
              + partial[2][mrow][mcol + c] + partial[3][mrow][mcol + c];
      Y[(long)mrow * DOUT + n0 + mcol + c] = v + bhy[n0 + mcol + c];
    }
  }
}

// ---------------------------------------------------------------------------
extern "C" void kernel_launch(void* const* d_in, const int* in_sizes, int n_in,
                              void* d_out, int out_size, void* d_ws, size_t ws_size,
                              hipStream_t stream) {
  const float* x   = (const float*)d_in[0];
  const float* Wxh = (const float*)d_in[1];
  const float* bxh = (const float*)d_in[2];
  const float* Whh = (const float*)d_in[3];
  const float* Why = (const float*)d_in[4];
  const float* bhy = (const float*)d_in[5];
  float* y = (float*)d_out;

  char* ws = (char*)d_ws;
  const size_t XH_BYTES  = (size_t)B_SZ * T_SZ * DH * 2;   // 128 MiB
  const size_t WHH_BYTES = (size_t)DH * DH * 2;            // 8 MiB
  const size_t WHY_BYTES = (size_t)DOUT * DH * 2;          // 4 MiB
  const size_t H_BYTES   = (size_t)2 * B_SZ * DH * 2;      // 512 KiB
  __hip_bfloat16* XH     = (__hip_bfloat16*)ws;
  __hip_bfloat16* Whh_bf = (__hip_bfloat16*)(ws + XH_BYTES);
  __hip_bfloat16* Why_bf = (__hip_bfloat16*)(ws + XH_BYTES + WHH_BYTES);
  __hip_bfloat16* hbuf   = (__hip_bfloat16*)(ws + XH_BYTES + WHH_BYTES + WHY_BYTES);
  unsigned* bar          = (unsigned*)(ws + XH_BYTES + WHH_BYTES + WHY_BYTES + H_BYTES);

  hipMemsetAsync(bar, 0, sizeof(unsigned), stream);
  f32_to_bf16<<<dim3((DH*DH)/(256*8)),   dim3(256), 0, stream>>>(Whh, Whh_bf, (long)DH*DH);
  f32_to_bf16<<<dim3((DOUT*DH)/(256*8)), dim3(256), 0, stream>>>(Why, Why_bf, (long)DOUT*DH);
  xh_gemm<<<dim3((32768/128) * (DH/128)), dim3(256), 0, stream>>>(x, Wxh, bxh, XH);
  elman_persistent<<<dim3(NBLK), dim3(256), 0, stream>>>(XH, Whh_bf, Why_bf, bhy, hbuf, y, bar);
}

// Round 4
// 9599.985 us; speedup vs baseline: 1.3817x; 1.0492x over previous
//
#include <hip/hip_runtime.h>
#include <hip/hip_bf16.h>

typedef __attribute__((ext_vector_type(8))) short bf16x8;   // 8 bf16 (4 VGPRs) MFMA A/B frag
typedef __attribute__((ext_vector_type(4))) float floatx4;  // MFMA C/D frag / 16B container

#define MFMA_BF16_16x16x32(a, b, c) __builtin_amdgcn_mfma_f32_16x16x32_bf16((a), (b), (c), 0, 0, 0)

#define B_SZ 64
#define T_SZ 512
#define DIN  1024
#define DH   2048
#define DOUT 1024
#define NBLK 64    // persistent grid: 64 blocks x 256 thr, co-resident
#define COLS 32    // h columns owned per block

union f4b8 { floatx4 f; bf16x8 b; };
__device__ inline bf16x8 asb(floatx4 f) { f4b8 u; u.f = f; return u.b; }

__device__ inline bf16x8 cvt8(float4 a, float4 b) {
  union { bf16x8 v; __hip_bfloat16 h[8]; } u;
  u.h[0] = __float2bfloat16(a.x); u.h[1] = __float2bfloat16(a.y);
  u.h[2] = __float2bfloat16(a.z); u.h[3] = __float2bfloat16(a.w);
  u.h[4] = __float2bfloat16(b.x); u.h[5] = __float2bfloat16(b.y);
  u.h[6] = __float2bfloat16(b.z); u.h[7] = __float2bfloat16(b.w);
  return u.v;
}

// Coherent (MALL-routed) h access: relaxed agent-scope atomics -> sc0+sc1,
// bypass L1/L2, served at the cross-XCD coherence point. No fences needed.
__device__ inline bf16x8 load_h16(const __hip_bfloat16* p) {
  union { bf16x8 v; unsigned long long q[2]; } u;
  const unsigned long long* q = (const unsigned long long*)p;
  u.q[0] = __hip_atomic_load(q,     __ATOMIC_RELAXED, __HIP_MEMORY_SCOPE_AGENT);
  u.q[1] = __hip_atomic_load(q + 1, __ATOMIC_RELAXED, __HIP_MEMORY_SCOPE_AGENT);
  return u.v;
}

// ---------------------------------------------------------------------------
// fp32 -> bf16 quantize (RNE), 8 elems/thread.
// ---------------------------------------------------------------------------
__global__ __launch_bounds__(256) void f32_to_bf16(
    const float* __restrict__ in, __hip_bfloat16* __restrict__ out, long n)
{
  long i = ((long)blockIdx.x * 256 + threadIdx.x) * 8;
  if (i + 8 <= n) {
    float4 a = *(const float4*)(in + i);
    float4 b = *(const float4*)(in + i + 4);
    *(bf16x8*)(out + i) = cvt8(a, b);
  }
}

// ---------------------------------------------------------------------------
// Kernel 1: XH = X @ Wxh^T + bxh  (fp32 in, bf16 out). 128x128 tile, BK=64.
// ---------------------------------------------------------------------------
__global__ __launch_bounds__(256) void xh_gemm(
    const float* __restrict__ X,
    const float* __restrict__ W,
    const float* __restrict__ bias,
    __hip_bfloat16* __restrict__ XH)
{
  const int K = DIN;
  const int N = DH;
  __shared__ __hip_bfloat16 As[128][64];
  __shared__ __hip_bfloat16 Bs[128][64];

  const int nb  = N / 128;
  const int bm  = blockIdx.x / nb;
  const int bn  = blockIdx.x % nb;
  const int m0  = bm * 128, n0 = bn * 128;
  const int tid = threadIdx.x;
  const int lane = tid & 63;
  const int wave = tid >> 6;
  const int wm  = (wave >> 1) * 64;
  const int wn  = (wave & 1) * 64;
  const int col = lane & 15;
  const int quad = lane >> 4;

  const floatx4 Z = {0.f, 0.f, 0.f, 0.f};
  floatx4 acc[4][4];
  #pragma unroll
  for (int i = 0; i < 4; ++i)
    #pragma unroll
    for (int j = 0; j < 4; ++j) acc[i][j] = Z;

  const int srow = tid >> 3;
  const int scol = (tid & 7) * 8;

  for (int k0 = 0; k0 < K; k0 += 64) {
    __syncthreads();
    #pragma unroll
    for (int p = 0; p < 4; ++p) {
      int r = srow + p * 32;
      const float* xs = &X[(long)(m0 + r) * K + k0 + scol];
      const float* wsrc = &W[(long)(n0 + r) * K + k0 + scol];
      *(bf16x8*)(&As[r][scol]) = cvt8(*(const float4*)xs,   *(const float4*)(xs + 4));
      *(bf16x8*)(&Bs[r][scol]) = cvt8(*(const float4*)wsrc, *(const float4*)(wsrc + 4));
    }
    __syncthreads();
    #pragma unroll
    for (int kk = 0; kk < 64; kk += 32) {
      const int kr = kk + quad * 8;
      bf16x8 a[4], b[4];
      #pragma unroll
      for (int i = 0; i < 4; ++i) a[i] = *(const bf16x8*)(&As[wm + i*16 + col][kr]);
      #pragma unroll
      for (int j = 0; j < 4; ++j) b[j] = *(const bf16x8*)(&Bs[wn + j*16 + col][kr]);
      #pragma unroll
      for (int i = 0; i < 4; ++i)
        #pragma unroll
        for (int j = 0; j < 4; ++j)
          acc[i][j] = MFMA_BF16_16x16x32(a[i], b[j], acc[i][j]);
    }
  }

  #pragma unroll
  for (int j = 0; j < 4; ++j) {
    const int n = n0 + wn + j*16 + col;
    const float bv = bias[n];
    #pragma unroll
    for (int i = 0; i < 4; ++i) {
      const int mr = m0 + wm + i*16 + quad*4;
      #pragma unroll
      for (int r = 0; r < 4; ++r)
        XH[(long)(mr + r) * N + n] = __float2bfloat16(acc[i][j][r] + bv);
    }
  }
}

// ---------------------------------------------------------------------------
// Flat-slot grid barrier (no RMW serialization):
//   arrival  = plain relaxed store of `want` into this block's padded slot
//   gather   = block 0 wave 0: lane l spins on slot[l] (64 parallel polls)
//   release  = block 0 tid 0 stores epoch = want; others spin on epoch
// vmcnt(0) before arrival drains this block's sc h-stores to the MALL, so
// slot-visibility implies h-visibility. Slots/epoch are monotonic.
// ---------------------------------------------------------------------------
__device__ inline void arrive_and_wait(unsigned* slots, unsigned* epoch,
                                       unsigned want, int bid) {
  asm volatile("s_waitcnt vmcnt(0)" ::: "memory");
  __syncthreads();
  const int tid = threadIdx.x;
  if (tid == 0)
    __hip_atomic_store(slots + (size_t)bid * 64, want,
                       __ATOMIC_RELAXED, __HIP_MEMORY_SCOPE_AGENT);
  if (bid == 0) {
    if (tid < 64) {
      while (__hip_atomic_load(slots + (size_t)tid * 64,
                               __ATOMIC_RELAXED, __HIP_MEMORY_SCOPE_AGENT) < want)
        __builtin_amdgcn_s_sleep(1);
      if (tid == 0)
        __hip_atomic_store(epoch, want, __ATOMIC_RELAXED, __HIP_MEMORY_SCOPE_AGENT);
    }
  } else if (tid == 0) {
    while (__hip_atomic_load(epoch, __ATOMIC_RELAXED, __HIP_MEMORY_SCOPE_AGENT) < want)
      __builtin_amdgcn_s_sleep(1);
  }
  __syncthreads();
}

// ---------------------------------------------------------------------------
// Kernel 2: persistent Elman recurrence + final projection.
//   64 blocks; block bid owns h cols [bid*32, bid*32+32). 1 block/CU.
//   Whh slice (2 n-tiles x 16 k-chunks = 128 VGPRs) pinned in registers via
//   asm anti-rematerialization. h exchanged via MALL (sc-flagged).
// ---------------------------------------------------------------------------
__global__ __launch_bounds__(256, 1) void elman_persistent(
    const __hip_bfloat16* __restrict__ XH,    // [64][512][2048] bf16
    const __hip_bfloat16* __restrict__ Whh,   // [2048][2048] bf16
    const __hip_bfloat16* __restrict__ Why,   // [1024][2048] bf16
    const float* __restrict__ bhy,            // [1024] fp32
    __hip_bfloat16* __restrict__ hbuf,        // [2][64][2048] bf16
    float* __restrict__ Y,                    // [64][1024] fp32 = d_out
    unsigned* __restrict__ slots,             // 64 x 256B
    unsigned* __restrict__ epoch)             // 1 x 256B
{
  __shared__ float partial[4][64][33];        // +1 pad: conflict-free reduce
  const int tid  = threadIdx.x;
  const int lane = tid & 63;
  const int wave = tid >> 6;
  const int bid  = blockIdx.x;
  const int n0   = bid * COLS;
  const int col  = lane & 15;
  const int quad = lane >> 4;
  const int kw   = wave * 512;

  const int mrow = tid >> 2;        // reduce/store: batch row (0..63)
  const int mcol = (tid & 3) * 8;   // reduce/store: col base within 32-slice

  // Pin Whh B-frags in registers: 2 n-tiles x 16 k-chunks = 128 VGPRs.
  // asm "+v" makes each fragment an opaque asm result -> cannot be
  // rematerialized from memory inside the t-loop.
  floatx4 wreg[2][16];
  #pragma unroll
  for (int n = 0; n < 2; ++n) {
    const __hip_bfloat16* wrow = Whh + (long)(n0 + n*16 + col) * DH + kw + quad * 8;
    #pragma unroll
    for (int k16 = 0; k16 < 16; ++k16) {
      wreg[n][k16] = *(const floatx4*)(wrow + k16 * 32);
      asm volatile("" : "+v"(wreg[n][k16]));
    }
  }

  // h0 = 0 for our slice (buffer 0), via coherent stores
  {
    unsigned long long* hp = (unsigned long long*)(hbuf + (long)mrow * DH + n0 + mcol);
    __hip_atomic_store(hp,     0ull, __ATOMIC_RELAXED, __HIP_MEMORY_SCOPE_AGENT);
    __hip_atomic_store(hp + 1, 0ull, __ATOMIC_RELAXED, __HIP_MEMORY_SCOPE_AGENT);
  }
  arrive_and_wait(slots, epoch, 1u, bid);

  int cur = 0;
  const floatx4 Z = {0.f, 0.f, 0.f, 0.f};

  for (int t = 0; t < T_SZ; ++t) {
    // Prefetch xh_t early: HBM latency hides behind the MFMA/h-load phase.
    bf16x8 xv = *(const bf16x8*)(XH + ((long)mrow * T_SZ + t) * DH + n0 + mcol);

    const __hip_bfloat16* h = hbuf + (long)cur * (B_SZ * DH);
    const __hip_bfloat16* hrow = h + (long)col * DH + kw + quad * 8;
    floatx4 acc[4][2];
    #pragma unroll
    for (int i = 0; i < 4; ++i) { acc[i][0] = Z; acc[i][1] = Z; }

    #pragma unroll
    for (int k16 = 0; k16 < 16; ++k16) {
      #pragma unroll
      for (int i = 0; i < 4; ++i) {
        bf16x8 a = load_h16(hrow + (long)i * 16 * DH + k16 * 32);
        acc[i][0] = MFMA_BF16_16x16x32(a, asb(wreg[0][k16]), acc[i][0]);
        acc[i][1] = MFMA_BF16_16x16x32(a, asb(wreg[1][k16]), acc[i][1]);
      }
    }
    // partials to LDS (C/D: m = i*16+quad*4+r, n = ntile*16+col)
    #pragma unroll
    for (int i = 0; i < 4; ++i)
      #pragma unroll
      for (int n = 0; n < 2; ++n)
        #pragma unroll
        for (int r = 0; r < 4; ++r)
          partial[wave][i*16 + quad*4 + r][n*16 + col] = acc[i][n][r];
    __syncthreads();
    // reduce 4 waves, + xh_t, relu, coherent-store bf16 h_next (8/thread)
    {
      __hip_bfloat16* hn = hbuf + (long)(1 - cur) * (B_SZ * DH);
      union { bf16x8 v8; __hip_bfloat16 hh[8]; unsigned long long q[2]; } o;
      union { bf16x8 v8; __hip_bfloat16 hh[8]; } xu; xu.v8 = xv;
      #pragma unroll
      for (int c = 0; c < 8; ++c) {
        float v = partial[0][mrow][mcol + c] + partial[1][mrow][mcol + c]
                + partial[2][mrow][mcol + c] + partial[3][mrow][mcol + c];
        v += __bfloat162float(xu.hh[c]);
        v = v > 0.f ? v : 0.f;
        o.hh[c] = __float2bfloat16(v);
      }
      unsigned long long* hp = (unsigned long long*)(hn + (long)mrow * DH + n0 + mcol);
      __hip_atomic_store(hp,     o.q[0], __ATOMIC_RELAXED, __HIP_MEMORY_SCOPE_AGENT);
      __hip_atomic_store(hp + 1, o.q[1], __ATOMIC_RELAXED, __HIP_MEMORY_SCOPE_AGENT);
    }
    arrive_and_wait(slots, epoch, (unsigned)(t + 2), bid);
    cur = 1 - cur;
  }

  // Final projection: y = h_final @ Why^T + bhy  (blocks 0..31, fp32 out)
  if (n0 < DOUT) {
    const __hip_bfloat16* h = hbuf + (long)cur * (B_SZ * DH);
    const __hip_bfloat16* hrow = h + (long)col * DH + kw + quad * 8;
    floatx4 acc[4][2];
    #pragma unroll
    for (int i = 0; i < 4; ++i) { acc[i][0] = Z; acc[i][1] = Z; }
    #pragma unroll
    for (int k16 = 0; k16 < 16; ++k16) {
      bf16x8 b0 = *(const bf16x8*)(Why + (long)(n0 +      col) * DH + kw + quad*8 + k16*32);
      bf16x8 b1 = *(const bf16x8*)(Why + (long)(n0 + 16 + col) * DH + kw + quad*8 + k16*32);
      #pragma unroll
      for (int i = 0; i < 4; ++i) {
        bf16x8 a = load_h16(hrow + (long)i * 16 * DH + k16 * 32);
        acc[i][0] = MFMA_BF16_16x16x32(a, b0, acc[i][0]);
        acc[i][1] = MFMA_BF16_16x16x32(a, b1, acc[i][1]);
      }
    }
    #pragma unroll
    for (int i = 0; i < 4; ++i)
      #pragma unroll
      for (int n = 0; n < 2; ++n)
        #pragma unroll
        for (int r = 0; r < 4; ++r)
          partial[wave][i*16 + quad*4 + r][n*16 + col] = acc[i][n][r];
    __syncthreads();
    #pragma unroll
    for (int c = 0; c < 8; ++c) {
      float v = partial[0][mrow][mcol + c] + partial[1][mrow][mcol + c]
              + partial[2][mrow][mcol + c] + partial[3][mrow][mcol + c];
      Y[(long)mrow * DOUT + n0 + mcol + c] = v + bhy[n0 + mcol + c];
    }
  }
}

// ---------------------------------------------------------------------------
extern "C" void kernel_launch(void* const* d_in, const int* in_sizes, int n_in,
                              void* d_out, int out_size, void* d_ws, size_t ws_size,
                              hipStream_t stream) {
  const float* x   = (const float*)d_in[0];
  const float* Wxh = (const float*)d_in[1];
  const float* bxh = (const float*)d_in[2];
  const float* Whh = (const float*)d_in[3];
  const float* Why = (const float*)d_in[4];
  const float* bhy = (const float*)d_in[5];
  float* y = (float*)d_out;

  char* ws = (char*)d_ws;
  const size_t XH_BYTES  = (size_t)B_SZ * T_SZ * DH * 2;   // 128 MiB
  const size_t WHH_BYTES = (size_t)DH * DH * 2;            // 8 MiB
  const size_t WHY_BYTES = (size_t)DOUT * DH * 2;          // 4 MiB
  const size_t H_BYTES   = (size_t)2 * B_SZ * DH * 2;      // 512 KiB
  const size_t BAR_BYTES = 65 * 256;                       // 64 slots + epoch
  __hip_bfloat16* XH     = (__hip_bfloat16*)ws;
  __hip_bfloat16* Whh_bf = (__hip_bfloat16*)(ws + XH_BYTES);
  __hip_bfloat16* Why_bf = (__hip_bfloat16*)(ws + XH_BYTES + WHH_BYTES);
  __hip_bfloat16* hbuf   = (__hip_bfloat16*)(ws + XH_BYTES + WHH_BYTES + WHY_BYTES);
  unsigned* slots        = (unsigned*)(ws + XH_BYTES + WHH_BYTES + WHY_BYTES + H_BYTES);
  unsigned* epoch        = slots + 64 * 64;                // 16 KiB in

  hipMemsetAsync(slots, 0, BAR_BYTES, stream);
  f32_to_bf16<<<dim3((DH*DH)/(256*8)),   dim3(256), 0, stream>>>(Whh, Whh_bf, (long)DH*DH);
  f32_to_bf16<<<dim3((DOUT*DH)/(256*8)), dim3(256), 0, stream>>>(Why, Why_bf, (long)DOUT*DH);
  xh_gemm<<<dim3((32768/128) * (DH/128)), dim3(256), 0, stream>>>(x, Wxh, bxh, XH);
  elman_persistent<<<dim3(NBLK), dim3(256), 0, stream>>>(
      XH, Whh_bf, Why_bf, bhy, hbuf, y, slots, epoch);
}

// Round 5
// 7404.458 us; speedup vs baseline: 1.7914x; 1.2965x over previous
//
#include <hip/hip_runtime.h>
#include <hip/hip_bf16.h>

typedef __attribute__((ext_vector_type(8))) short bf16x8;   // 8 bf16 MFMA A/B frag
typedef __attribute__((ext_vector_type(4))) float floatx4;  // MFMA C/D frag / 16B container

#define MFMA_BF16_16x16x32(a, b, c) __builtin_amdgcn_mfma_f32_16x16x32_bf16((a), (b), (c), 0, 0, 0)

#define B_SZ 64
#define T_SZ 512
#define DIN  1024
#define DH   2048
#define DOUT 1024
#define NBLK 64    // persistent grid: 64 blocks x 256 thr, co-resident
#define COLS 32    // h columns owned per block
#define HWORDS (DH/2 * B_SZ)   // dwords per h buffer (k-pair-major [1024][64])

union f4b8 { floatx4 f; bf16x8 b; };
__device__ inline bf16x8 asb(floatx4 f) { f4b8 u; u.f = f; return u.b; }

__device__ inline unsigned ld_coh(const unsigned* p) {
  return __hip_atomic_load(p, __ATOMIC_RELAXED, __HIP_MEMORY_SCOPE_AGENT);
}
__device__ inline void st_coh(unsigned* p, unsigned v) {
  __hip_atomic_store(p, v, __ATOMIC_RELAXED, __HIP_MEMORY_SCOPE_AGENT);
}

__device__ inline bf16x8 cvt8(float4 a, float4 b) {
  union { bf16x8 v; __hip_bfloat16 h[8]; } u;
  u.h[0] = __float2bfloat16(a.x); u.h[1] = __float2bfloat16(a.y);
  u.h[2] = __float2bfloat16(a.z); u.h[3] = __float2bfloat16(a.w);
  u.h[4] = __float2bfloat16(b.x); u.h[5] = __float2bfloat16(b.y);
  u.h[6] = __float2bfloat16(b.z); u.h[7] = __float2bfloat16(b.w);
  return u.v;
}

// ---------------------------------------------------------------------------
// fp32 -> bf16 quantize (RNE), 8 elems/thread.
// ---------------------------------------------------------------------------
__global__ __launch_bounds__(256) void f32_to_bf16(
    const float* __restrict__ in, __hip_bfloat16* __restrict__ out, long n)
{
  long i = ((long)blockIdx.x * 256 + threadIdx.x) * 8;
  if (i + 8 <= n) {
    float4 a = *(const float4*)(in + i);
    float4 b = *(const float4*)(in + i + 4);
    *(bf16x8*)(out + i) = cvt8(a, b);
  }
}

// ---------------------------------------------------------------------------
// Kernel 1: XH = X @ Wxh^T + bxh  (fp32 in, bf16 out). 128x128 tile, BK=64.
// ---------------------------------------------------------------------------
__global__ __launch_bounds__(256) void xh_gemm(
    const float* __restrict__ X,
    const float* __restrict__ W,
    const float* __restrict__ bias,
    __hip_bfloat16* __restrict__ XH)
{
  const int K = DIN;
  const int N = DH;
  __shared__ __hip_bfloat16 As[128][64];
  __shared__ __hip_bfloat16 Bs[128][64];

  const int nb  = N / 128;
  const int bm  = blockIdx.x / nb;
  const int bn  = blockIdx.x % nb;
  const int m0  = bm * 128, n0 = bn * 128;
  const int tid = threadIdx.x;
  const int lane = tid & 63;
  const int wave = tid >> 6;
  const int wm  = (wave >> 1) * 64;
  const int wn  = (wave & 1) * 64;
  const int col = lane & 15;
  const int quad = lane >> 4;

  const floatx4 Z = {0.f, 0.f, 0.f, 0.f};
  floatx4 acc[4][4];
  #pragma unroll
  for (int i = 0; i < 4; ++i)
    #pragma unroll
    for (int j = 0; j < 4; ++j) acc[i][j] = Z;

  const int srow = tid >> 3;
  const int scol = (tid & 7) * 8;

  for (int k0 = 0; k0 < K; k0 += 64) {
    __syncthreads();
    #pragma unroll
    for (int p = 0; p < 4; ++p) {
      int r = srow + p * 32;
      const float* xs = &X[(long)(m0 + r) * K + k0 + scol];
      const float* wsrc = &W[(long)(n0 + r) * K + k0 + scol];
      *(bf16x8*)(&As[r][scol]) = cvt8(*(const float4*)xs,   *(const float4*)(xs + 4));
      *(bf16x8*)(&Bs[r][scol]) = cvt8(*(const float4*)wsrc, *(const float4*)(wsrc + 4));
    }
    __syncthreads();
    #pragma unroll
    for (int kk = 0; kk < 64; kk += 32) {
      const int kr = kk + quad * 8;
      bf16x8 a[4], b[4];
      #pragma unroll
      for (int i = 0; i < 4; ++i) a[i] = *(const bf16x8*)(&As[wm + i*16 + col][kr]);
      #pragma unroll
      for (int j = 0; j < 4; ++j) b[j] = *(const bf16x8*)(&Bs[wn + j*16 + col][kr]);
      #pragma unroll
      for (int i = 0; i < 4; ++i)
        #pragma unroll
        for (int j = 0; j < 4; ++j)
          acc[i][j] = MFMA_BF16_16x16x32(a[i], b[j], acc[i][j]);
    }
  }

  #pragma unroll
  for (int j = 0; j < 4; ++j) {
    const int n = n0 + wn + j*16 + col;
    const float bv = bias[n];
    #pragma unroll
    for (int i = 0; i < 4; ++i) {
      const int mr = m0 + wm + i*16 + quad*4;
      #pragma unroll
      for (int r = 0; r < 4; ++r)
        XH[(long)(mr + r) * N + n] = __float2bfloat16(acc[i][j][r] + bv);
    }
  }
}

// ---------------------------------------------------------------------------
// Flat-slot grid barrier, no central release: every block's wave 0 polls all
// 64 slots in parallel (lane l <-> slot l). Monotonic epochs, no reset.
// vmcnt(0) drains this block's sc h-stores to the coherence point first.
// ---------------------------------------------------------------------------
__device__ inline void arrive_and_wait(unsigned* slots, unsigned want, int bid) {
  asm volatile("s_waitcnt vmcnt(0)" ::: "memory");
  __syncthreads();
  const int tid = threadIdx.x;
  if (tid == 0)
    st_coh(slots + (size_t)bid * 64, want);
  if (tid < 64) {
    while (ld_coh(slots + (size_t)tid * 64) < want)
      __builtin_amdgcn_s_sleep(1);
  }
  __syncthreads();
}

// ---------------------------------------------------------------------------
// Kernel 2: persistent Elman recurrence + final projection.
//   h kept in k-pair-major layout: hbuf dword[(k>>1)*64 + m] = {bf16(k,m),
//   bf16(k+1,m)}. A-fragment = 4 dword loads, 16 consecutive lanes 4B apart
//   -> fully coalesced MALL traffic (4 lines/instr vs 64 before).
// ---------------------------------------------------------------------------
__global__ __launch_bounds__(256, 1) void elman_persistent(
    const __hip_bfloat16* __restrict__ XH,    // [64][512][2048] bf16
    const __hip_bfloat16* __restrict__ Whh,   // [2048][2048] bf16
    const __hip_bfloat16* __restrict__ Why,   // [1024][2048] bf16
    const float* __restrict__ bhy,            // [1024] fp32
    unsigned* __restrict__ hbuf,              // [2][1024][64] dwords, k-pair-major
    float* __restrict__ Y,                    // [64][1024] fp32 = d_out
    unsigned* __restrict__ slots)             // 64 x 256B
{
  __shared__ float partial[4][64][33];        // +1 pad: conflict-free reduce
  const int tid  = threadIdx.x;
  const int lane = tid & 63;
  const int wave = tid >> 6;
  const int bid  = blockIdx.x;
  const int n0   = bid * COLS;
  const int col  = lane & 15;
  const int quad = lane >> 4;
  const int kw   = wave * 512;      // this wave's K range base
  const int npb  = kw >> 1;         // wave's base k-pair index

  const int mrow = tid >> 2;        // reduce/store: batch row (0..63)
  const int g    = tid & 3;         // reduce/store: 8-col group within slice
  const int mcol = g * 8;

  // Pin Whh B-frags (asm anti-remat; AGPR residency is fine too).
  floatx4 wreg[2][16];
  #pragma unroll
  for (int n = 0; n < 2; ++n) {
    const __hip_bfloat16* wrow = Whh + (long)(n0 + n*16 + col) * DH + kw + quad * 8;
    #pragma unroll
    for (int k16 = 0; k16 < 16; ++k16) {
      wreg[n][k16] = *(const floatx4*)(wrow + k16 * 32);
      asm volatile("" : "+v"(wreg[n][k16]));
    }
  }

  // h0 = 0 for our slice (buffer 0): 4 dwords/thread, coalesced
  #pragma unroll
  for (int j = 0; j < 4; ++j)
    st_coh(hbuf + (size_t)(n0/2 + g*4 + j) * 64 + mrow, 0u);
  arrive_and_wait(slots, 1u, bid);

  // XH stream: this thread's 16B chunk per t; prefetched one step ahead.
  const __hip_bfloat16* xptr = XH + (long)mrow * T_SZ * DH + n0 + mcol;
  bf16x8 xv = *(const bf16x8*)xptr;   // t = 0

  int cur = 0;
  const floatx4 Z = {0.f, 0.f, 0.f, 0.f};

  for (int t = 0; t < T_SZ; ++t) {
    bf16x8 xv_next = xv;
    if (t + 1 < T_SZ) xv_next = *(const bf16x8*)(xptr + (long)(t + 1) * DH);

    const unsigned* hc = hbuf + (size_t)cur * HWORDS;
    floatx4 acc[4][2];
    #pragma unroll
    for (int i = 0; i < 4; ++i) { acc[i][0] = Z; acc[i][1] = Z; }

    #pragma unroll
    for (int k16 = 0; k16 < 16; ++k16) {
      const unsigned* pk = hc + (size_t)(npb + k16*16 + quad*4) * 64 + col;
      #pragma unroll
      for (int i = 0; i < 4; ++i) {
        union { unsigned u[4]; bf16x8 v; } a;
        const unsigned* p = pk + i * 16;
        a.u[0] = ld_coh(p);        // k-pairs {0,1}
        a.u[1] = ld_coh(p + 64);   // {2,3}
        a.u[2] = ld_coh(p + 128);  // {4,5}
        a.u[3] = ld_coh(p + 192);  // {6,7}
        acc[i][0] = MFMA_BF16_16x16x32(a.v, asb(wreg[0][k16]), acc[i][0]);
        acc[i][1] = MFMA_BF16_16x16x32(a.v, asb(wreg[1][k16]), acc[i][1]);
      }
    }
    // partials to LDS (C/D: m = i*16+quad*4+r, n = nt*16+col)
    #pragma unroll
    for (int i = 0; i < 4; ++i)
      #pragma unroll
      for (int n = 0; n < 2; ++n)
        #pragma unroll
        for (int r = 0; r < 4; ++r)
          partial[wave][i*16 + quad*4 + r][n*16 + col] = acc[i][n][r];
    __syncthreads();
    // reduce 4 waves, + xh_t, relu, pack n-pairs, coalesced coherent stores
    {
      unsigned* hn = hbuf + (size_t)(1 - cur) * HWORDS;
      union { bf16x8 v8; __hip_bfloat16 hh[8]; unsigned q[4]; } o;
      union { bf16x8 v8; __hip_bfloat16 hh[8]; } xu; xu.v8 = xv;
      #pragma unroll
      for (int c = 0; c < 8; ++c) {
        float v = partial[0][mrow][mcol + c] + partial[1][mrow][mcol + c]
                + partial[2][mrow][mcol + c] + partial[3][mrow][mcol + c];
        v += __bfloat162float(xu.hh[c]);
        v = v > 0.f ? v : 0.f;
        o.hh[c] = __float2bfloat16(v);
      }
      #pragma unroll
      for (int j = 0; j < 4; ++j)
        st_coh(hn + (size_t)(n0/2 + g*4 + j) * 64 + mrow, o.q[j]);
    }
    arrive_and_wait(slots, (unsigned)(t + 2), bid);
    cur = 1 - cur;
    xv = xv_next;
  }

  // Final projection: y = h_final @ Why^T + bhy  (blocks 0..31, fp32 out)
  if (n0 < DOUT) {
    const unsigned* hc = hbuf + (size_t)cur * HWORDS;
    floatx4 acc[4][2];
    #pragma unroll
    for (int i = 0; i < 4; ++i) { acc[i][0] = Z; acc[i][1] = Z; }
    #pragma unroll
    for (int k16 = 0; k16 < 16; ++k16) {
      bf16x8 b0 = *(const bf16x8*)(Why + (long)(n0 +      col) * DH + kw + quad*8 + k16*32);
      bf16x8 b1 = *(const bf16x8*)(Why + (long)(n0 + 16 + col) * DH + kw + quad*8 + k16*32);
      const unsigned* pk = hc + (size_t)(npb + k16*16 + quad*4) * 64 + col;
      #pragma unroll
      for (int i = 0; i < 4; ++i) {
        union { unsigned u[4]; bf16x8 v; } a;
        const unsigned* p = pk + i * 16;
        a.u[0] = ld_coh(p);  a.u[1] = ld_coh(p + 64);
        a.u[2] = ld_coh(p + 128); a.u[3] = ld_coh(p + 192);
        acc[i][0] = MFMA_BF16_16x16x32(a.v, b0, acc[i][0]);
        acc[i][1] = MFMA_BF16_16x16x32(a.v, b1, acc[i][1]);
      }
    }
    #pragma unroll
    for (int i = 0; i < 4; ++i)
      #pragma unroll
      for (int n = 0; n < 2; ++n)
        #pragma unroll
        for (int r = 0; r < 4; ++r)
          partial[wave][i*16 + quad*4 + r][n*16 + col] = acc[i][n][r];
    __syncthreads();
    #pragma unroll
    for (int c = 0; c < 8; ++c) {
      float v = partial[0][mrow][mcol + c] + partial[1][mrow][mcol + c]
              + partial[2][mrow][mcol + c] + partial[3][mrow][mcol + c];
      Y[(long)mrow * DOUT + n0 + mcol + c] = v + bhy[n0 + mcol + c];
    }
  }
}

// ---------------------------------------------------------------------------
extern "C" void kernel_launch(void* const* d_in, const int* in_sizes, int n_in,
                              void* d_out, int out_size, void* d_ws, size_t ws_size,
                              hipStream_t stream) {
  const float* x   = (const float*)d_in[0];
  const float* Wxh = (const float*)d_in[1];
  const float* bxh = (const float*)d_in[2];
  const float* Whh = (const float*)d_in[3];
  const float* Why = (const float*)d_in[4];
  const float* bhy = (const float*)d_in[5];
  float* y = (float*)d_out;

  char* ws = (char*)d_ws;
  const size_t XH_BYTES  = (size_t)B_SZ * T_SZ * DH * 2;   // 128 MiB
  const size_t WHH_BYTES = (size_t)DH * DH * 2;            // 8 MiB
  const size_t WHY_BYTES = (size_t)DOUT * DH * 2;          // 4 MiB
  const size_t H_BYTES   = (size_t)2 * HWORDS * 4;         // 512 KiB
  const size_t BAR_BYTES = 64 * 256;                       // 64 slots
  __hip_bfloat16* XH     = (__hip_bfloat16*)ws;
  __hip_bfloat16* Whh_bf = (__hip_bfloat16*)(ws + XH_BYTES);
  __hip_bfloat16* Why_bf = (__hip_bfloat16*)(ws + XH_BYTES + WHH_BYTES);
  unsigned* hbuf         = (unsigned*)(ws + XH_BYTES + WHH_BYTES + WHY_BYTES);
  unsigned* slots        = (unsigned*)(ws + XH_BYTES + WHH_BYTES + WHY_BYTES + H_BYTES);

  hipMemsetAsync(slots, 0, BAR_BYTES, stream);
  f32_to_bf16<<<dim3((DH*DH)/(256*8)),   dim3(256), 0, stream>>>(Whh, Whh_bf, (long)DH*DH);
  f32_to_bf16<<<dim3((DOUT*DH)/(256*8)), dim3(256), 0, stream>>>(Why, Why_bf, (long)DOUT*DH);
  xh_gemm<<<dim3((32768/128) * (DH/128)), dim3(256), 0, stream>>>(x, Wxh, bxh, XH);
  elman_persistent<<<dim3(NBLK), dim3(256), 0, stream>>>(
      XH, Whh_bf, Why_bf, bhy, hbuf, y, slots);
}